// Round 9
// baseline (973.077 us; speedup 1.0000x reference)
//
#include <hip/hip_runtime.h>
#include <math.h>
#include <stdint.h>

#define E_N 19
#define H_N 32
#define T_N 2048
#define B_N 64
#define G_N 128      // 4*H gate rows per chain
#define XCHUNK 32    // timesteps staged per LDS round (per chain, one per lane-half)
#define LOG2E 1.4426950408889634f

typedef _Float16 half2_t __attribute__((ext_vector_type(2)));

__device__ __forceinline__ float sigm_rcp(float e) {  // 1/(1+e)
    return __builtin_amdgcn_rcpf(1.0f + e);
}

// One WAVE per TWO chains. j = lane&31 = hidden unit, half = lane>>5 = which chain.
// Each lane owns ALL FOUR gate rows (i,f,g,o) of its hidden unit -> the c/h update
// is fully lane-local: no shuffles, no junk-half duplication. Cross-step state is
// h only, broadcast via per-half LDS (4x uniform ds_read_b128, 2-way = free).
// 64 packed fp16 weight VGPRs/lane; waves_per_eu(2,2) gives ~256-reg budget so
// residency is cheap for the allocator; pins block load-sinking.
__global__ __launch_bounds__(64)
__attribute__((amdgpu_waves_per_eu(2, 2)))
void lstm_chain_kernel(
    const float* __restrict__ x,     // [B, T, E]
    const float* __restrict__ w_ih,  // [E, 2, 4H]
    const float* __restrict__ w_hh,  // [E, 2, 4H, H]
    const float* __restrict__ b_ih,  // [E, 2, 4H]
    const float* __restrict__ b_hh,  // [E, 2, 4H]
    float* __restrict__ hT)          // [B, E, 2, H]
{
    const int lane  = threadIdx.x;
    const int j     = lane & 31;
    const int half  = lane >> 5;
    const int chain = blockIdx.x * 2 + half;     // b*(E*2) + e*2 + d
    const int b  = chain / (E_N * 2);
    const int ed = chain - b * (E_N * 2);
    const int e  = ed >> 1;
    const int d  = ed & 1;

    // ---- load 4 gate rows (i,f,g,o) of unit j, quantize to packed fp16 ----
    uint32_t wp[4][16];          // 64 VGPRs
    float    wih[4], bias[4];
    #pragma unroll
    for (int gi = 0; gi < 4; ++gi) {
        const int   row = j + 32 * gi;
        const float* wr = w_hh + ((size_t)ed * G_N + row) * H_N;
        #pragma unroll
        for (int m = 0; m < 16; ++m) {
            float2 v = ((const float2*)wr)[m];
            half2_t p = { (_Float16)v.x, (_Float16)v.y };
            wp[gi][m] = __builtin_bit_cast(uint32_t, p);
        }
        wih[gi]  = w_ih[(size_t)ed * G_N + row];
        bias[gi] = b_ih[(size_t)ed * G_N + row] + b_hh[(size_t)ed * G_N + row];
    }

    // LDS: per-chain h (32 fp16 = 64 B) + per-chain x chunk
    __shared__ __align__(16) uint16_t hbuf[2][H_N];
    __shared__ float xbuf[2][XCHUNK];

    hbuf[half][j] = 0;           // single wave per block: in-order DS, no barrier
    float c = 0.0f;
    float h = 0.0f;

    const float* xbase = x + (size_t)b * T_N * E_N + e;

    for (int t0 = 0; t0 < T_N; t0 += XCHUNK) {
        // PIN: keep all 64 packed weight regs live across the inner loop (no-op).
        #pragma unroll
        for (int m = 0; m < 16; ++m) {
            asm volatile("" : "+v"(wp[0][m]), "+v"(wp[1][m]),
                              "+v"(wp[2][m]), "+v"(wp[3][m]));
        }

        // stage 32 timesteps for this half's chain (reversed time for d==1)
        const int tt    = t0 + j;
        const int tphys = d ? (T_N - 1 - tt) : tt;
        xbuf[half][j] = xbase[(size_t)tphys * E_N];

        #pragma unroll 1
        for (int tl = 0; tl < XCHUNK; ++tl) {
            // h broadcast: 4x b128, address uniform per half (2-way = free)
            const uint4* hb = (const uint4*)hbuf[half];
            const uint4 q0 = hb[0];
            const uint4 q1 = hb[1];
            const uint4 q2 = hb[2];
            const uint4 q3 = hb[3];
            const float sx = xbuf[half][tl];

            uint32_t hp[16];
            hp[0]=q0.x; hp[1]=q0.y; hp[2]=q0.z; hp[3]=q0.w;
            hp[4]=q1.x; hp[5]=q1.y; hp[6]=q1.z; hp[7]=q1.w;
            hp[8]=q2.x; hp[9]=q2.y; hp[10]=q2.z; hp[11]=q2.w;
            hp[12]=q3.x; hp[13]=q3.y; hp[14]=q3.z; hp[15]=q3.w;

            float ga[4], gb[4];
            #pragma unroll
            for (int gi = 0; gi < 4; ++gi) {
                ga[gi] = fmaf(sx, wih[gi], bias[gi]);
                gb[gi] = 0.0f;
            }
            #pragma unroll
            for (int m = 0; m < 8; ++m) {
                #pragma unroll
                for (int gi = 0; gi < 4; ++gi) {
                    ga[gi] = __builtin_amdgcn_fdot2(
                        __builtin_bit_cast(half2_t, hp[m]),
                        __builtin_bit_cast(half2_t, wp[gi][m]),   ga[gi], false);
                    gb[gi] = __builtin_amdgcn_fdot2(
                        __builtin_bit_cast(half2_t, hp[m+8]),
                        __builtin_bit_cast(half2_t, wp[gi][m+8]), gb[gi], false);
                }
            }
            const float gi_v = ga[0] + gb[0];
            const float gf_v = ga[1] + gb[1];
            const float gg_v = ga[2] + gb[2];
            const float go_v = ga[3] + gb[3];

            const float si = sigm_rcp(__builtin_amdgcn_exp2f(gi_v * (-LOG2E)));
            const float sf = sigm_rcp(__builtin_amdgcn_exp2f(gf_v * (-LOG2E)));
            const float tg = fmaf(2.0f, sigm_rcp(
                __builtin_amdgcn_exp2f(gg_v * (-2.0f * LOG2E))), -1.0f);
            const float so = sigm_rcp(__builtin_amdgcn_exp2f(go_v * (-LOG2E)));

            c = fmaf(sf, c, si * tg);
            const float tc = fmaf(2.0f, sigm_rcp(
                __builtin_amdgcn_exp2f(c * (-2.0f * LOG2E))), -1.0f);
            h = so * tc;

            hbuf[half][j] = __builtin_bit_cast(uint16_t, (_Float16)h);
        }
    }

    // every lane writes its unit's final h for its chain
    hT[((size_t)(b * E_N + e) * 2 + d) * H_N + j] = h;
}

// LayerNorm over 64 feats per (b,e), mean over e, FC -> out[b]. One wave per b.
__global__ __launch_bounds__(64) void head_kernel(
    const float* __restrict__ hT,      // [B, E, 64]
    const float* __restrict__ ln_gamma,// [E, 64]
    const float* __restrict__ ln_beta, // [E, 64]
    const float* __restrict__ fc_w,    // [64]
    const float* __restrict__ fc_b,    // [1]
    float* __restrict__ out)           // [B]
{
    const int b = blockIdx.x;
    const int f = threadIdx.x; // 0..63

    float acc = 0.0f;
    for (int e = 0; e < E_N; ++e) {
        const float v = hT[(size_t)(b * E_N + e) * 64 + f];
        float s = v, s2 = v * v;
        #pragma unroll
        for (int off = 32; off > 0; off >>= 1) {
            s  += __shfl_xor(s,  off);
            s2 += __shfl_xor(s2, off);
        }
        const float mean = s * (1.0f / 64.0f);
        const float var  = s2 * (1.0f / 64.0f) - mean * mean;
        const float inv  = rsqrtf(var + 1e-5f);
        acc += (v - mean) * inv * ln_gamma[e * 64 + f] + ln_beta[e * 64 + f];
    }
    float contrib = (acc * (1.0f / (float)E_N)) * fc_w[f];
    #pragma unroll
    for (int off = 32; off > 0; off >>= 1) contrib += __shfl_xor(contrib, off);
    if (f == 0) out[b] = contrib + fc_b[0];
}

extern "C" void kernel_launch(void* const* d_in, const int* in_sizes, int n_in,
                              void* d_out, int out_size, void* d_ws, size_t ws_size,
                              hipStream_t stream) {
    const float* x        = (const float*)d_in[0];
    const float* w_ih     = (const float*)d_in[1];
    const float* w_hh     = (const float*)d_in[2];
    const float* b_ih     = (const float*)d_in[3];
    const float* b_hh     = (const float*)d_in[4];
    const float* ln_gamma = (const float*)d_in[5];
    const float* ln_beta  = (const float*)d_in[6];
    const float* fc_w     = (const float*)d_in[7];
    const float* fc_b     = (const float*)d_in[8];
    float* out = (float*)d_out;
    float* hT  = (float*)d_ws;  // B*E*2*H floats

    lstm_chain_kernel<<<(B_N * E_N * 2) / 2, 64, 0, stream>>>(x, w_ih, w_hh, b_ih, b_hh, hT);
    head_kernel<<<B_N, 64, 0, stream>>>(hT, ln_gamma, ln_beta, fc_w, fc_b, out);
}